// Round 7
// baseline (939.466 us; speedup 1.0000x reference)
//
#include <hip/hip_runtime.h>

// mLSTM (UniRep-style), T=2048, B=4096, I=1, H=5.
// Identity (I==1): gates = x*(Wih + W3 @ h) + (b_ih+b_hh),
//   W3[r][j] = sum_k Whh[r][k]*Wmx[k]*Wmh[k][j]  (constant 20x5) -> plain LSTM cell.
//
// Latency-bound: a single in-order wave has ~4 independent strands and leaves
// most trans/DPP dependency latency as dead issue slots (R2/R4/R5 all ~350
// cy/step despite different mixes). Fix: ILP=4 — each lane advances FOUR
// independent batch chains, interleaved in the unrolled body, so dependency
// stalls of one chain are filled with ready work from the others. Weights are
// shared across slots; per-slot state is ~23 VGPRs.
//
// Per-chain structure = R5 (passing): 8 lanes/chain; lanes 0-4 own cell j=l,
// lanes 5-7 duplicate cell 4 so the h4 broadcast is one row_shl:4 DPP.
// Gate preacts pre-scaled by -log2e (i,f,o) / -2log2e (g); c kept in -2log2e
// domain. cs' = K2*(ri*rg) + (rf*cs + K3*ri). h = fma(2*so, R, -so).
// DPP rule (verified R1/R4/R5): row_shr:N -> lane i <- i-N ; row_shl:N -> i <- i+N.
//
// (R6 was an UnresponsiveContainer infra failure; this is the same kernel.)

#define TT 2048
#define BB 4096
#define HH 5
#define ILP 4   // independent chains per lane

template<int CTRL, int RM, int BM>
__device__ __forceinline__ float dpp_upd(float old_, float src) {
    int o = __builtin_bit_cast(int, old_);
    int s = __builtin_bit_cast(int, src);
    int r = __builtin_amdgcn_update_dpp(o, s, CTRL, RM, BM, false);
    return __builtin_bit_cast(float, r);
}

__global__ __launch_bounds__(64) void mlstm_kernel(
    const float* __restrict__ xb,    // [T, B]
    const float* __restrict__ h0,    // [B, H]
    const float* __restrict__ c0,    // [B, H]
    const float* __restrict__ Wmx,   // [H]
    const float* __restrict__ Wmh,   // [H, H]
    const float* __restrict__ Wih,   // [4H]
    const float* __restrict__ Whh,   // [4H, H]
    const float* __restrict__ b_ih,  // [4H]
    const float* __restrict__ b_hh,  // [4H]
    float* __restrict__ out)         // [B, H] = relu(h_T)
{
    const int g   = (threadIdx.x >> 3);        // lane-group 0..7
    const int l8  = threadIdx.x & 7;
    const int j   = (l8 < HH) ? l8 : 4;        // lanes 5-7 duplicate cell 4
    // chain for ILP slot s: b = blockIdx.x*(8*ILP) + s*8 + g
    const int b0  = blockIdx.x * (8 * ILP) + g;

    const float NL2E  = -1.442695040888963f;   // -log2(e)
    const float N2L2E = -2.885390081777927f;   // -2*log2(e)
    const float K2 = 2.f * N2L2E;
    const float K3 = -N2L2E;

    // ---- one-time per-thread weight fold (shared by all ILP slots) ----
    float W3[4][HH], wih[4], bias[4];
#pragma unroll
    for (int q = 0; q < 4; ++q) {              // 0=i 1=f 2=g 3=o ; row r = j + 5q
        const float sq = (q == 2) ? N2L2E : NL2E;
        const int r = j + HH * q;
        wih[q]  = sq * Wih[r];
        bias[q] = sq * (b_ih[r] + b_hh[r]);
#pragma unroll
        for (int k = 0; k < HH; ++k) {
            float s = 0.f;
#pragma unroll
            for (int m = 0; m < HH; ++m)
                s = fmaf(Whh[r * HH + m] * Wmx[m], Wmh[m * HH + k], s);
            W3[q][k] = sq * s;
        }
    }

    // ---- per-slot state ----
    float cs[ILP], hk0[ILP], hk1[ILP], hk2[ILP], hk3[ILP], hk4[ILP], ho[ILP];
    float xc[ILP][8], xn[ILP][8];
#pragma unroll
    for (int s = 0; s < ILP; ++s) {
        const int bs = b0 + s * 8;
        cs[s]  = N2L2E * c0[bs * HH + j];
        hk0[s] = h0[bs * HH + 0];
        hk1[s] = h0[bs * HH + 1];
        hk2[s] = h0[bs * HH + 2];
        hk3[s] = h0[bs * HH + 3];
        hk4[s] = h0[bs * HH + 4];
        ho[s]  = 0.f;
#pragma unroll
        for (int j8 = 0; j8 < 8; ++j8) xc[s][j8] = xb[j8 * BB + bs];
    }

    for (int tb = 0; tb < TT / 8; ++tb) {
        const int tn = (tb + 1 < TT / 8) ? (tb + 1) : tb;   // clamped: harmless reload
#pragma unroll
        for (int s = 0; s < ILP; ++s)
#pragma unroll
            for (int j8 = 0; j8 < 8; ++j8)
                xn[s][j8] = xb[(tn * 8 + j8) * BB + (b0 + s * 8)];

#pragma unroll
        for (int j8 = 0; j8 < 8; ++j8) {
#pragma unroll
            for (int s = 0; s < ILP; ++s) {
                const float xv = xc[s][j8];

                // gate preacts, balanced 2-chain trees
                float gg[4];
#pragma unroll
                for (int q = 0; q < 4; ++q) {
                    const float m4 = W3[q][4] * hk4[s];
                    const float C  = fmaf(W3[q][3], hk3[s], m4);
                    const float C2 = fmaf(W3[q][2], hk2[s], C);
                    const float A  = fmaf(W3[q][0], hk0[s], wih[q]);
                    const float A2 = fmaf(W3[q][1], hk1[s], A);
                    gg[q] = fmaf(xv, A2 + C2, bias[q]);
                }

                // activations: r = rcp(1+exp2(pre)); saturating, clamp-free
                const float ei = __builtin_amdgcn_exp2f(gg[0]);
                const float ef = __builtin_amdgcn_exp2f(gg[1]);
                const float eg = __builtin_amdgcn_exp2f(gg[2]);
                const float eo = __builtin_amdgcn_exp2f(gg[3]);
                const float ri = __builtin_amdgcn_rcpf(1.f + ei);  // sigma(i)
                const float rf = __builtin_amdgcn_rcpf(1.f + ef);  // sigma(f)
                const float rg = __builtin_amdgcn_rcpf(1.f + eg);  // sigma(2g)
                const float ro = __builtin_amdgcn_rcpf(1.f + eo);  // sigma(o)

                // cs' = rf*cs + ri*(K2*rg + K3)
                const float m   = ri * rg;
                const float k3i = K3 * ri;
                const float t   = fmaf(rf, cs[s], k3i);
                cs[s] = fmaf(K2, m, t);

                const float s2o = ro + ro;
                const float nso = -ro;

                // h = sigma(o)*tanh(c) = 2*so*R - so,  R = rcp(1+exp2(cs))
                const float ec = __builtin_amdgcn_exp2f(cs[s]);
                const float R  = __builtin_amdgcn_rcpf(1.f + ec);
                const float hn = fmaf(s2o, R, nso);
                ho[s] = hn;

                // broadcast h0..h4 to all 8 lanes of the group (per slot)
                hk4[s] = dpp_upd<0x104, 0xF, 0x5>(hn, hn);      // row_shl:4, depth 1
                float v0 = dpp_upd<0x00, 0xF, 0x5>(hn, hn);
                float v1 = dpp_upd<0x55, 0xF, 0x5>(hn, hn);
                float v2 = dpp_upd<0xAA, 0xF, 0x5>(hn, hn);
                float v3 = dpp_upd<0xFF, 0xF, 0x5>(hn, hn);
                hk0[s] = dpp_upd<0x114, 0xF, 0xA>(v0, v0);      // row_shr:4
                hk1[s] = dpp_upd<0x114, 0xF, 0xA>(v1, v1);
                hk2[s] = dpp_upd<0x114, 0xF, 0xA>(v2, v2);
                hk3[s] = dpp_upd<0x114, 0xF, 0xA>(v3, v3);
            }
        }

#pragma unroll
        for (int s = 0; s < ILP; ++s)
#pragma unroll
            for (int j8 = 0; j8 < 8; ++j8) xc[s][j8] = xn[s][j8];
    }

    if (l8 < HH) {
#pragma unroll
        for (int s = 0; s < ILP; ++s)
            out[(b0 + s * 8) * HH + l8] = fmaxf(ho[s], 0.f);
    }
}

extern "C" void kernel_launch(void* const* d_in, const int* in_sizes, int n_in,
                              void* d_out, int out_size, void* d_ws, size_t ws_size,
                              hipStream_t stream) {
    const float* xb   = (const float*)d_in[0];
    const float* h0   = (const float*)d_in[1];
    const float* c0   = (const float*)d_in[2];
    const float* Wmx  = (const float*)d_in[3];
    const float* Wmh  = (const float*)d_in[4];
    const float* Wih  = (const float*)d_in[5];
    const float* Whh  = (const float*)d_in[6];
    const float* b_ih = (const float*)d_in[7];
    const float* b_hh = (const float*)d_in[8];
    float* out = (float*)d_out;

    const int grid = BB / (8 * ILP);   // 128 one-wave blocks, 32 chains/wave
    mlstm_kernel<<<grid, 64, 0, stream>>>(xb, h0, c0, Wmx, Wmh, Wih, Whh, b_ih, b_hh, out);
}

// Round 8
// 935.835 us; speedup vs baseline: 1.0039x; 1.0039x over previous
//
#include <hip/hip_runtime.h>

// mLSTM (UniRep-style), T=2048, B=4096, I=1, H=5.
// Identity (I==1): gates = x*(Wih + W3 @ h) + (b_ih+b_hh),
//   W3[r][j] = sum_k Whh[r][k]*Wmx[k]*Wmh[k][j]  (constant 20x5) -> plain LSTM cell.
//
// ILP=4: each lane advances FOUR independent batch chains, interleaved in the
// unrolled body, so dependency stalls (exp2/rcp/DPP latency) of one chain are
// filled with ready work from the others. Weights shared across slots.
//
// R7 lesson: without the 2nd __launch_bounds__ arg the compiler capped the
// kernel at 68 VGPRs and spilled ~90 floats of state to scratch -> 3x slower
// (VALUBusy 11%). __launch_bounds__(64, 1) = min 1 wave/EU -> ~512-VGPR budget,
// state (~160 regs) fits with no spill. Occupancy is irrelevant here (latency-
// bound, 128 waves on 1024 SIMDs).
//
// Per-chain structure = R5 (passing): 8 lanes/chain; lanes 0-4 own cell j=l,
// lanes 5-7 duplicate cell 4 so the h4 broadcast is one row_shl:4 DPP.
// Gate preacts pre-scaled by -log2e (i,f,o) / -2log2e (g); c kept in -2log2e
// domain. cs' = K2*(ri*rg) + (rf*cs + K3*ri). h = fma(2*so, R, -so).
// DPP rule (verified R1/R4/R5): row_shr:N -> lane i <- i-N ; row_shl:N -> i <- i+N.

#define TT 2048
#define BB 4096
#define HH 5
#define ILP 4   // independent chains per lane

template<int CTRL, int RM, int BM>
__device__ __forceinline__ float dpp_upd(float old_, float src) {
    int o = __builtin_bit_cast(int, old_);
    int s = __builtin_bit_cast(int, src);
    int r = __builtin_amdgcn_update_dpp(o, s, CTRL, RM, BM, false);
    return __builtin_bit_cast(float, r);
}

__global__ __launch_bounds__(64, 1) void mlstm_kernel(
    const float* __restrict__ xb,    // [T, B]
    const float* __restrict__ h0,    // [B, H]
    const float* __restrict__ c0,    // [B, H]
    const float* __restrict__ Wmx,   // [H]
    const float* __restrict__ Wmh,   // [H, H]
    const float* __restrict__ Wih,   // [4H]
    const float* __restrict__ Whh,   // [4H, H]
    const float* __restrict__ b_ih,  // [4H]
    const float* __restrict__ b_hh,  // [4H]
    float* __restrict__ out)         // [B, H] = relu(h_T)
{
    const int g   = (threadIdx.x >> 3);        // lane-group 0..7
    const int l8  = threadIdx.x & 7;
    const int j   = (l8 < HH) ? l8 : 4;        // lanes 5-7 duplicate cell 4
    // chain for ILP slot s: b = blockIdx.x*(8*ILP) + s*8 + g
    const int b0  = blockIdx.x * (8 * ILP) + g;

    const float NL2E  = -1.442695040888963f;   // -log2(e)
    const float N2L2E = -2.885390081777927f;   // -2*log2(e)
    const float K2 = 2.f * N2L2E;
    const float K3 = -N2L2E;

    // ---- one-time per-thread weight fold (shared by all ILP slots) ----
    float W3[4][HH], wih[4], bias[4];
#pragma unroll
    for (int q = 0; q < 4; ++q) {              // 0=i 1=f 2=g 3=o ; row r = j + 5q
        const float sq = (q == 2) ? N2L2E : NL2E;
        const int r = j + HH * q;
        wih[q]  = sq * Wih[r];
        bias[q] = sq * (b_ih[r] + b_hh[r]);
#pragma unroll
        for (int k = 0; k < HH; ++k) {
            float s = 0.f;
#pragma unroll
            for (int m = 0; m < HH; ++m)
                s = fmaf(Whh[r * HH + m] * Wmx[m], Wmh[m * HH + k], s);
            W3[q][k] = sq * s;
        }
    }

    // ---- per-slot state ----
    float cs[ILP], hk0[ILP], hk1[ILP], hk2[ILP], hk3[ILP], hk4[ILP], ho[ILP];
    float xc[ILP][8], xn[ILP][8];
#pragma unroll
    for (int s = 0; s < ILP; ++s) {
        const int bs = b0 + s * 8;
        cs[s]  = N2L2E * c0[bs * HH + j];
        hk0[s] = h0[bs * HH + 0];
        hk1[s] = h0[bs * HH + 1];
        hk2[s] = h0[bs * HH + 2];
        hk3[s] = h0[bs * HH + 3];
        hk4[s] = h0[bs * HH + 4];
        ho[s]  = 0.f;
#pragma unroll
        for (int j8 = 0; j8 < 8; ++j8) xc[s][j8] = xb[j8 * BB + bs];
    }

    for (int tb = 0; tb < TT / 8; ++tb) {
        const int tn = (tb + 1 < TT / 8) ? (tb + 1) : tb;   // clamped: harmless reload
#pragma unroll
        for (int s = 0; s < ILP; ++s)
#pragma unroll
            for (int j8 = 0; j8 < 8; ++j8)
                xn[s][j8] = xb[(tn * 8 + j8) * BB + (b0 + s * 8)];

#pragma unroll
        for (int j8 = 0; j8 < 8; ++j8) {
#pragma unroll
            for (int s = 0; s < ILP; ++s) {
                const float xv = xc[s][j8];

                // gate preacts, balanced 2-chain trees
                float gg[4];
#pragma unroll
                for (int q = 0; q < 4; ++q) {
                    const float m4 = W3[q][4] * hk4[s];
                    const float C  = fmaf(W3[q][3], hk3[s], m4);
                    const float C2 = fmaf(W3[q][2], hk2[s], C);
                    const float A  = fmaf(W3[q][0], hk0[s], wih[q]);
                    const float A2 = fmaf(W3[q][1], hk1[s], A);
                    gg[q] = fmaf(xv, A2 + C2, bias[q]);
                }

                // activations: r = rcp(1+exp2(pre)); saturating, clamp-free
                const float ei = __builtin_amdgcn_exp2f(gg[0]);
                const float ef = __builtin_amdgcn_exp2f(gg[1]);
                const float eg = __builtin_amdgcn_exp2f(gg[2]);
                const float eo = __builtin_amdgcn_exp2f(gg[3]);
                const float ri = __builtin_amdgcn_rcpf(1.f + ei);  // sigma(i)
                const float rf = __builtin_amdgcn_rcpf(1.f + ef);  // sigma(f)
                const float rg = __builtin_amdgcn_rcpf(1.f + eg);  // sigma(2g)
                const float ro = __builtin_amdgcn_rcpf(1.f + eo);  // sigma(o)

                // cs' = rf*cs + ri*(K2*rg + K3)
                const float m   = ri * rg;
                const float k3i = K3 * ri;
                const float t   = fmaf(rf, cs[s], k3i);
                cs[s] = fmaf(K2, m, t);

                const float s2o = ro + ro;
                const float nso = -ro;

                // h = sigma(o)*tanh(c) = 2*so*R - so,  R = rcp(1+exp2(cs))
                const float ec = __builtin_amdgcn_exp2f(cs[s]);
                const float R  = __builtin_amdgcn_rcpf(1.f + ec);
                const float hn = fmaf(s2o, R, nso);
                ho[s] = hn;

                // broadcast h0..h4 to all 8 lanes of the group (per slot)
                hk4[s] = dpp_upd<0x104, 0xF, 0x5>(hn, hn);      // row_shl:4, depth 1
                float v0 = dpp_upd<0x00, 0xF, 0x5>(hn, hn);
                float v1 = dpp_upd<0x55, 0xF, 0x5>(hn, hn);
                float v2 = dpp_upd<0xAA, 0xF, 0x5>(hn, hn);
                float v3 = dpp_upd<0xFF, 0xF, 0x5>(hn, hn);
                hk0[s] = dpp_upd<0x114, 0xF, 0xA>(v0, v0);      // row_shr:4
                hk1[s] = dpp_upd<0x114, 0xF, 0xA>(v1, v1);
                hk2[s] = dpp_upd<0x114, 0xF, 0xA>(v2, v2);
                hk3[s] = dpp_upd<0x114, 0xF, 0xA>(v3, v3);
            }
        }

#pragma unroll
        for (int s = 0; s < ILP; ++s)
#pragma unroll
            for (int j8 = 0; j8 < 8; ++j8) xc[s][j8] = xn[s][j8];
    }

    if (l8 < HH) {
#pragma unroll
        for (int s = 0; s < ILP; ++s)
            out[(b0 + s * 8) * HH + l8] = fmaxf(ho[s], 0.f);
    }
}

extern "C" void kernel_launch(void* const* d_in, const int* in_sizes, int n_in,
                              void* d_out, int out_size, void* d_ws, size_t ws_size,
                              hipStream_t stream) {
    const float* xb   = (const float*)d_in[0];
    const float* h0   = (const float*)d_in[1];
    const float* c0   = (const float*)d_in[2];
    const float* Wmx  = (const float*)d_in[3];
    const float* Wmh  = (const float*)d_in[4];
    const float* Wih  = (const float*)d_in[5];
    const float* Whh  = (const float*)d_in[6];
    const float* b_ih = (const float*)d_in[7];
    const float* b_hh = (const float*)d_in[8];
    float* out = (float*)d_out;

    const int grid = BB / (8 * ILP);   // 128 one-wave blocks, 32 chains/wave
    mlstm_kernel<<<grid, 64, 0, stream>>>(xb, h0, c0, Wmx, Wmh, Wih, Whh, b_ih, b_hh, out);
}